// Round 3
// baseline (109.942 us; speedup 1.0000x reference)
//
#include <hip/hip_runtime.h>
#include <hip/hip_bf16.h>

#define B_SZ 256
#define L_SZ 50
#define N_SZ 100000
#define D_SZ 128
#define NT ((N_SZ + 63) / 64)   // 1563 col-tiles of 64

typedef __attribute__((ext_vector_type(8))) short bf16x8;
typedef __attribute__((ext_vector_type(4))) float f32x4;

__device__ inline unsigned short f2bf(float f) {
    union { float f; unsigned u; } v; v.f = f;
    unsigned r = v.u + 0x7FFFu + ((v.u >> 16) & 1u);   // round-to-nearest-even
    return (unsigned short)(r >> 16);
}

// ---------------- kernel 1: qW1[d] = sum_e q[e] W1[e,d]; qW2; qsum; zero loss slot
__global__ __launch_bounds__(128) void k_prep(const float* __restrict__ W1,
                                              const float* __restrict__ W2,
                                              const float* __restrict__ q,
                                              float* __restrict__ wsf,
                                              float* __restrict__ loss_slot) {
    int d = threadIdx.x;
    float a1 = 0.f, a2 = 0.f;
    #pragma unroll 4
    for (int e = 0; e < D_SZ; ++e) {
        float qe = q[e];
        a1 += qe * W1[e * D_SZ + d];
        a2 += qe * W2[e * D_SZ + d];
    }
    wsf[d] = a1;
    wsf[D_SZ + d] = a2;
    __shared__ float red[D_SZ];
    red[d] = q[d];
    __syncthreads();
    if (d == 0) {
        float s = 0.f;
        for (int i = 0; i < D_SZ; ++i) s += red[i];
        wsf[2 * D_SZ] = s;      // qsum
        loss_slot[0] = 0.f;     // zero loss accumulator every launch
    }
}

// ---------------- kernel 2: per-b, gather v, compute att, u -> bf16
__global__ __launch_bounds__(128) void k_ub(const int* __restrict__ seeds,
                                            const float* __restrict__ E,
                                            const float* __restrict__ pe,
                                            const float* __restrict__ wsf,
                                            const float* __restrict__ b_att,
                                            unsigned short* __restrict__ u_bf) {
    __shared__ float vbuf[L_SZ][D_SZ + 1];   // +1 pad: bank-conflict-free row sweeps
    __shared__ float att[L_SZ];
    __shared__ float c2s;
    __shared__ float qw1s[D_SZ], qw2s[D_SZ];
    int b = blockIdx.x, d = threadIdx.x;
    qw1s[d] = wsf[d];
    qw2s[d] = wsf[D_SZ + d];

    for (int l = 0; l < L_SZ; ++l) {
        int s = seeds[b * L_SZ + l];
        vbuf[l][d] = E[(size_t)s * D_SZ + d] + pe[l * D_SZ + d];
    }
    __syncthreads();

    if (d < L_SZ) {                 // att_raw[l] = v[l,:] . qW1
        float acc = 0.f;
        #pragma unroll 4
        for (int k = 0; k < D_SZ; ++k) acc += vbuf[d][k] * qw1s[k];
        att[d] = acc;
    } else if (d == L_SZ) {         // c2 = vn . qW2
        float acc = 0.f;
        #pragma unroll 4
        for (int k = 0; k < D_SZ; ++k) acc += vbuf[L_SZ - 1][k] * qw2s[k];
        c2s = acc;
    }
    __syncthreads();

    float add = c2s + b_att[0] * wsf[2 * D_SZ];
    float u = 0.f;
    #pragma unroll 5
    for (int l = 0; l < L_SZ; ++l) u += (att[l] + add) * vbuf[l][d];
    u_bf[b * D_SZ + d] = f2bf(u);
}

// ---------------- kernel 3: scores = u @ E^T + bias (bf16 MFMA, swapped operands)
// A = E-panel (16 n-cols as A-rows), B = u (b-rows as B-cols).
// D layout: row=(lane>>4)*4+g -> n-offset, col=lane&15 -> b-row.
// => each lane holds 4 CONSECUTIVE n for ONE b-row -> 16B vector stores.
__global__ __launch_bounds__(256) void k_gemm(const float* __restrict__ E,
                                              const float* __restrict__ out_bias,
                                              const unsigned short* __restrict__ u_bf,
                                              float* __restrict__ scores,
                                              float* __restrict__ partial) {
    __shared__ float lds_sum[B_SZ];
    int tid = threadIdx.x;
    int w = tid >> 6, lane = tid & 63;
    lds_sum[tid] = 0.f;
    __syncthreads();

    int nc = blockIdx.x * 64 + w * 16;       // this wave's 16-col panel
    bool valid = (nc < N_SZ);                // wave-uniform (N_SZ % 16 == 0)
    int lo = lane & 15, hi = lane >> 4;
    int kb = hi * 8;

    // A fragments: E rows (= score cols), cast f32->bf16.  A[m][k]: m=lo, k=kb+j
    long erow = valid ? (nc + lo) : 0;
    bf16x8 efrag[4];
    #pragma unroll
    for (int ks = 0; ks < 4; ++ks) {
        const float* p = E + (size_t)erow * D_SZ + ks * 32 + kb;
        float4 x = *(const float4*)p;
        float4 y = *(const float4*)(p + 4);
        bf16x8 f;
        f[0] = (short)f2bf(x.x); f[1] = (short)f2bf(x.y);
        f[2] = (short)f2bf(x.z); f[3] = (short)f2bf(x.w);
        f[4] = (short)f2bf(y.x); f[5] = (short)f2bf(y.y);
        f[6] = (short)f2bf(y.z); f[7] = (short)f2bf(y.w);
        efrag[ks] = f;
    }
    int nb = valid ? (nc + hi * 4) : 0;      // this lane's 4 consecutive n
    float4 bias4 = *(const float4*)(out_bias + nb);

    // 16 persistent accumulators; ks-outer so the 16 u-loads + 16 MFMAs per ks
    // are all independent (full ILP, L2 latency hidden in-wave).
    f32x4 acc[16];
    #pragma unroll
    for (int i = 0; i < 16; ++i) acc[i] = (f32x4){0.f, 0.f, 0.f, 0.f};

    #pragma unroll
    for (int ks = 0; ks < 4; ++ks) {
        #pragma unroll
        for (int rs = 0; rs < 16; ++rs) {
            bf16x8 uf = *(const bf16x8*)(u_bf + (rs * 16 + lo) * D_SZ + ks * 32 + kb);
            acc[rs] = __builtin_amdgcn_mfma_f32_16x16x32_bf16(efrag[ks], uf, acc[rs], 0, 0, 0);
        }
    }

    #pragma unroll
    for (int rs = 0; rs < 16; ++rs) {
        int jr = rs * 16 + lo;               // this lane's b-row
        f32x4 c;
        c[0] = acc[rs][0] + bias4.x;
        c[1] = acc[rs][1] + bias4.y;
        c[2] = acc[rs][2] + bias4.z;
        c[3] = acc[rs][3] + bias4.w;
        if (valid)
            __builtin_nontemporal_store(c, (f32x4*)(scores + (size_t)jr * N_SZ + nb));
        float p = __expf(c[0]) + __expf(c[1]) + __expf(c[2]) + __expf(c[3]);
        p += __shfl_xor(p, 16);
        p += __shfl_xor(p, 32);              // lanes {l, l^16, l^32, l^48} share jr
        if (valid && hi == 0) atomicAdd(&lds_sum[jr], p);
    }
    __syncthreads();
    partial[(size_t)blockIdx.x * B_SZ + tid] = lds_sum[tid];
}

// ---------------- kernel 4: per-row logsumexp + NLL mean
__global__ __launch_bounds__(256) void k_loss(const float* __restrict__ partial,
                                              const float* __restrict__ scores,
                                              const int* __restrict__ labels,
                                              float* __restrict__ out_loss) {
    int b = blockIdx.x, t = threadIdx.x;
    float acc = 0.f;
    for (int i = t; i < NT; i += 256) acc += partial[(size_t)i * B_SZ + b];
    __shared__ float red[256];
    red[t] = acc;
    __syncthreads();
    for (int s = 128; s > 0; s >>= 1) {
        if (t < s) red[t] += red[t + s];
        __syncthreads();
    }
    if (t == 0) {
        int lab = labels[b];
        float val = scores[(size_t)b * N_SZ + lab] - logf(red[0]);
        atomicAdd(out_loss, -val * (1.0f / (float)B_SZ));
    }
}

extern "C" void kernel_launch(void* const* d_in, const int* in_sizes, int n_in,
                              void* d_out, int out_size, void* d_ws, size_t ws_size,
                              hipStream_t stream) {
    const int*   seeds    = (const int*)d_in[0];
    const int*   labels   = (const int*)d_in[1];
    const float* E        = (const float*)d_in[2];
    const float* W1       = (const float*)d_in[3];
    const float* W2       = (const float*)d_in[4];
    const float* q        = (const float*)d_in[5];
    const float* b_att    = (const float*)d_in[6];
    const float* out_bias = (const float*)d_in[7];
    const float* pe       = (const float*)d_in[8];

    float* scores = (float*)d_out;
    float* loss   = scores + (size_t)B_SZ * N_SZ;

    // ws layout: [0,512) qW1 | [512,1024) qW2 | [1024] qsum | @2048 u_bf16 (64KB) | @67584 partial (1.6MB)
    float*          wsf     = (float*)d_ws;
    unsigned short* u_bf    = (unsigned short*)((char*)d_ws + 2048);
    float*          partial = (float*)((char*)d_ws + 67584);

    k_prep<<<1, 128, 0, stream>>>(W1, W2, q, wsf, loss);
    k_ub<<<B_SZ, 128, 0, stream>>>(seeds, E, pe, wsf, b_att, u_bf);
    k_gemm<<<NT, 256, 0, stream>>>(E, out_bias, u_bf, scores, partial);
    k_loss<<<B_SZ, 256, 0, stream>>>(partial, scores, labels, loss);
}

// Round 4
// 62.885 us; speedup vs baseline: 1.7483x; 1.7483x over previous
//
#include <hip/hip_runtime.h>
#include <hip/hip_bf16.h>

#define B_SZ 256
#define L_SZ 50
#define N_SZ 100000
#define D_SZ 128
#define NB ((N_SZ + 127) / 128)   // 782 col-tiles of 128 (tail tile = 32 cols)

typedef __attribute__((ext_vector_type(8))) short bf16x8;
typedef __attribute__((ext_vector_type(4))) float f32x4;

__device__ inline unsigned short f2bf(float f) {
    union { float f; unsigned u; } v; v.f = f;
    unsigned r = v.u + 0x7FFFu + ((v.u >> 16) & 1u);   // round-to-nearest-even
    return (unsigned short)(r >> 16);
}

// ---------------- kernel 1: qW1[d] = sum_e q[e] W1[e,d]; qW2; qsum; zero loss slot
__global__ __launch_bounds__(128) void k_prep(const float* __restrict__ W1,
                                              const float* __restrict__ W2,
                                              const float* __restrict__ q,
                                              float* __restrict__ wsf,
                                              float* __restrict__ loss_slot) {
    int d = threadIdx.x;
    float a1 = 0.f, a2 = 0.f;
    #pragma unroll 4
    for (int e = 0; e < D_SZ; ++e) {
        float qe = q[e];
        a1 += qe * W1[e * D_SZ + d];
        a2 += qe * W2[e * D_SZ + d];
    }
    wsf[d] = a1;
    wsf[D_SZ + d] = a2;
    __shared__ float red[D_SZ];
    red[d] = q[d];
    __syncthreads();
    if (d == 0) {
        float s = 0.f;
        for (int i = 0; i < D_SZ; ++i) s += red[i];
        wsf[2 * D_SZ] = s;      // qsum
        loss_slot[0] = 0.f;     // zero loss accumulator every launch
    }
}

// ---------------- kernel 2: per-b, gather v, compute att, u -> bf16
__global__ __launch_bounds__(128) void k_ub(const int* __restrict__ seeds,
                                            const float* __restrict__ E,
                                            const float* __restrict__ pe,
                                            const float* __restrict__ wsf,
                                            const float* __restrict__ b_att,
                                            unsigned short* __restrict__ u_bf) {
    __shared__ float vbuf[L_SZ][D_SZ + 1];   // +1 pad: bank-conflict-free row sweeps
    __shared__ float att[L_SZ];
    __shared__ float c2s;
    __shared__ float qw1s[D_SZ], qw2s[D_SZ];
    int b = blockIdx.x, d = threadIdx.x;
    qw1s[d] = wsf[d];
    qw2s[d] = wsf[D_SZ + d];

    for (int l = 0; l < L_SZ; ++l) {
        int s = seeds[b * L_SZ + l];
        vbuf[l][d] = E[(size_t)s * D_SZ + d] + pe[l * D_SZ + d];
    }
    __syncthreads();

    if (d < L_SZ) {                 // att_raw[l] = v[l,:] . qW1
        float acc = 0.f;
        #pragma unroll 4
        for (int k = 0; k < D_SZ; ++k) acc += vbuf[d][k] * qw1s[k];
        att[d] = acc;
    } else if (d == L_SZ) {         // c2 = vn . qW2
        float acc = 0.f;
        #pragma unroll 4
        for (int k = 0; k < D_SZ; ++k) acc += vbuf[L_SZ - 1][k] * qw2s[k];
        c2s = acc;
    }
    __syncthreads();

    float add = c2s + b_att[0] * wsf[2 * D_SZ];
    float u = 0.f;
    #pragma unroll 5
    for (int l = 0; l < L_SZ; ++l) u += (att[l] + add) * vbuf[l][d];
    u_bf[b * D_SZ + d] = f2bf(u);
}

// ---------------- kernel 3: scores = u @ E^T + bias (bf16 MFMA)
// 512 threads = 8 waves; block covers 128 n-cols. u (256x128 bf16 = 64 KB)
// staged in LDS, XOR-swizzled (byte ^= (b&7)<<4) for conflict-free ds_read_b128.
// A = E-panel rows (n), B = u cols (b). D: row=(lane>>4)*4+g -> n, col=lane&15 -> b
// => each lane: 4 consecutive n for one b-row -> 16B vector stores (allocating).
__global__ __launch_bounds__(512, 4) void k_gemm(const float* __restrict__ E,
                                                 const float* __restrict__ out_bias,
                                                 const unsigned short* __restrict__ u_bf,
                                                 float* __restrict__ scores,
                                                 float* __restrict__ partial) {
    __shared__ unsigned short us[B_SZ * D_SZ];   // 64 KB swizzled u
    __shared__ float lds_sum[B_SZ];
    int tid = threadIdx.x;
    int w = tid >> 6, lane = tid & 63;
    if (tid < B_SZ) lds_sum[tid] = 0.f;

    // ---- stage u: coalesced 16B/thread global reads, swizzled LDS writes
    #pragma unroll
    for (int r = 0; r < 8; ++r) {
        int d = r * 8192 + tid * 16;             // flat byte offset into u_bf
        int b = d >> 8, inrow = d & 255;
        bf16x8 v = *(const bf16x8*)((const char*)u_bf + d);
        *(bf16x8*)((char*)us + b * 256 + (inrow ^ ((b & 7) << 4))) = v;
    }

    int nc = blockIdx.x * 128 + w * 16;          // this wave's 16-col panel
    bool valid = (nc < N_SZ);                    // wave-uniform (N_SZ % 16 == 0)
    int lo = lane & 15, hi = lane >> 4;
    int kb = hi * 8;

    // ---- A fragments: E rows (= score cols), f32 -> bf16 in regs
    long erow = valid ? (nc + lo) : 0;
    bf16x8 efrag[4];
    #pragma unroll
    for (int ks = 0; ks < 4; ++ks) {
        const float* p = E + (size_t)erow * D_SZ + ks * 32 + kb;
        float4 x = *(const float4*)p;
        float4 y = *(const float4*)(p + 4);
        bf16x8 f;
        f[0] = (short)f2bf(x.x); f[1] = (short)f2bf(x.y);
        f[2] = (short)f2bf(x.z); f[3] = (short)f2bf(x.w);
        f[4] = (short)f2bf(y.x); f[5] = (short)f2bf(y.y);
        f[6] = (short)f2bf(y.z); f[7] = (short)f2bf(y.w);
        efrag[ks] = f;
    }
    int nb = valid ? (nc + hi * 4) : 0;          // this lane's 4 consecutive n
    float4 bias4 = *(const float4*)(out_bias + nb);

    __syncthreads();                             // u staged; lds_sum zeroed

    // ---- 16 persistent accumulators; ks-outer: 16 independent ds_reads+MFMAs
    f32x4 acc[16];
    #pragma unroll
    for (int i = 0; i < 16; ++i) acc[i] = (f32x4){0.f, 0.f, 0.f, 0.f};

    #pragma unroll
    for (int ks = 0; ks < 4; ++ks) {
        int kcol = ks * 64 + hi * 16;            // byte offset of 16B k-chunk
        #pragma unroll
        for (int rs = 0; rs < 16; ++rs) {
            int b = rs * 16 + lo;
            bf16x8 uf = *(const bf16x8*)((const char*)us + b * 256 + (kcol ^ ((b & 7) << 4)));
            acc[rs] = __builtin_amdgcn_mfma_f32_16x16x32_bf16(efrag[ks], uf, acc[rs], 0, 0, 0);
        }
    }

    #pragma unroll
    for (int rs = 0; rs < 16; ++rs) {
        int jr = rs * 16 + lo;                   // this lane's b-row
        f32x4 c;
        c[0] = acc[rs][0] + bias4.x;
        c[1] = acc[rs][1] + bias4.y;
        c[2] = acc[rs][2] + bias4.z;
        c[3] = acc[rs][3] + bias4.w;
        if (valid)
            *(f32x4*)(scores + (size_t)jr * N_SZ + nb) = c;   // allocating store
        float p = __expf(c[0]) + __expf(c[1]) + __expf(c[2]) + __expf(c[3]);
        p += __shfl_xor(p, 16);
        p += __shfl_xor(p, 32);                  // lanes {l, l^16, l^32, l^48} share jr
        if (valid && hi == 0) atomicAdd(&lds_sum[jr], p);
    }
    __syncthreads();
    if (tid < B_SZ) partial[(size_t)blockIdx.x * B_SZ + tid] = lds_sum[tid];
}

// ---------------- kernel 4: per-row logsumexp + NLL mean
__global__ __launch_bounds__(256) void k_loss(const float* __restrict__ partial,
                                              const float* __restrict__ scores,
                                              const int* __restrict__ labels,
                                              float* __restrict__ out_loss) {
    int b = blockIdx.x, t = threadIdx.x;
    float acc = 0.f;
    for (int i = t; i < NB; i += 256) acc += partial[(size_t)i * B_SZ + b];
    __shared__ float red[256];
    red[t] = acc;
    __syncthreads();
    for (int s = 128; s > 0; s >>= 1) {
        if (t < s) red[t] += red[t + s];
        __syncthreads();
    }
    if (t == 0) {
        int lab = labels[b];
        float val = scores[(size_t)b * N_SZ + lab] - logf(red[0]);
        atomicAdd(out_loss, -val * (1.0f / (float)B_SZ));
    }
}

extern "C" void kernel_launch(void* const* d_in, const int* in_sizes, int n_in,
                              void* d_out, int out_size, void* d_ws, size_t ws_size,
                              hipStream_t stream) {
    const int*   seeds    = (const int*)d_in[0];
    const int*   labels   = (const int*)d_in[1];
    const float* E        = (const float*)d_in[2];
    const float* W1       = (const float*)d_in[3];
    const float* W2       = (const float*)d_in[4];
    const float* q        = (const float*)d_in[5];
    const float* b_att    = (const float*)d_in[6];
    const float* out_bias = (const float*)d_in[7];
    const float* pe       = (const float*)d_in[8];

    float* scores = (float*)d_out;
    float* loss   = scores + (size_t)B_SZ * N_SZ;

    // ws layout: [0,512) qW1 | [512,1024) qW2 | [1024] qsum | @2048 u_bf16 (64KB) | @67584 partial (800KB)
    float*          wsf     = (float*)d_ws;
    unsigned short* u_bf    = (unsigned short*)((char*)d_ws + 2048);
    float*          partial = (float*)((char*)d_ws + 67584);

    k_prep<<<1, 128, 0, stream>>>(W1, W2, q, wsf, loss);
    k_ub<<<B_SZ, 128, 0, stream>>>(seeds, E, pe, wsf, b_att, u_bf);
    k_gemm<<<NB, 512, 0, stream>>>(E, out_bias, u_bf, scores, partial);
    k_loss<<<B_SZ, 256, 0, stream>>>(partial, scores, labels, loss);
}